// Round 4
// baseline (341.226 us; speedup 1.0000x reference)
//
#include <hip/hip_runtime.h>

typedef unsigned short u16;
typedef __attribute__((ext_vector_type(8))) short short8;
typedef __attribute__((ext_vector_type(8))) unsigned short u16x8;
typedef __attribute__((ext_vector_type(4))) unsigned short u16x4;
typedef __attribute__((ext_vector_type(4))) float f32x4;

#define N_TOKENS 32768
#define EMBED 512
#define NCLS 16
#define NBATCH 8
#define NHEAD 8
#define DHEAD 64

__device__ __forceinline__ u16 f2bf(float f) {
  unsigned u = __float_as_uint(f);
  u += 0x7fffu + ((u >> 16) & 1u);   // RNE
  return (u16)(u >> 16);
}
__device__ __forceinline__ float bf2f(u16 b) {
  return __uint_as_float(((unsigned)b) << 16);
}

__device__ __forceinline__ void async16(const u16* g, u16* l) {
  __builtin_amdgcn_global_load_lds(
      (__attribute__((address_space(1))) const unsigned int*)(const void*)g,
      (__attribute__((address_space(3))) unsigned int*)(void*)l,
      16, 0, 0);
}

// ---------------- fp32 -> bf16 converter (4 elems/thread) ----------------
__global__ __launch_bounds__(256) void cvt_bf16(const float4* __restrict__ in,
                                                u16x4* __restrict__ out, int n4) {
  int i = blockIdx.x * blockDim.x + threadIdx.x;
  if (i >= n4) return;
  float4 v = in[i];
  u16x4 o;
  o[0] = f2bf(v.x); o[1] = f2bf(v.y); o[2] = f2bf(v.z); o[3] = f2bf(v.w);
  out[i] = o;
}

// ---------------- K/V projection into attention-friendly layouts ----------------
// kproj[b][h][d][l] = sum_e key[l][b][e]*Wk[h*64+d][e] + bk
// vproj[b][h][l][d] = sum_e val[l][b][e]*Wv[h*64+d][e] + bv
__global__ __launch_bounds__(256) void kvproj_kernel(
    const float* __restrict__ key, const float* __restrict__ val,
    const float* __restrict__ Wk, const float* __restrict__ bk,
    const float* __restrict__ Wv, const float* __restrict__ bv,
    float* __restrict__ kproj, float* __restrict__ vproj) {
  int t = blockIdx.x * blockDim.x + threadIdx.x;   // [0, 2*65536)
  const bool isV = t >= 65536;                      // wave-uniform (65536 % 64 == 0)
  int idx = t & 65535;
  int f = idx & 511;
  int bl = idx >> 9;
  int l = bl & 15;
  int b = bl >> 4;
  const float* src = isV ? val : key;
  const float* W = isV ? Wv : Wk;
  const float* bias = isV ? bv : bk;
  const float4* s4 = (const float4*)(src + (size_t)l * (NBATCH * EMBED) + (size_t)b * EMBED);
  const float4* w4 = (const float4*)(W + (size_t)f * EMBED);
  float acc = 0.f;
#pragma unroll 8
  for (int e = 0; e < EMBED / 4; e++) {
    float4 a = s4[e], w = w4[e];
    acc += a.x * w.x + a.y * w.y + a.z * w.z + a.w * w.w;
  }
  acc += bias[f];
  if (!isV) {
    kproj[((size_t)(b * EMBED + f)) * NCLS + l] = acc;           // [b][h][d][l]
  } else {
    int h = f >> 6, d = f & 63;
    vproj[(size_t)b * (NHEAD * NCLS * DHEAD) + (size_t)h * (NCLS * DHEAD) + l * DHEAD + d] = acc;
  }
}

// ---------------- bf16 GEMM: C[M,N] = A[M,K] * B[N,K]^T + bias ----------------
// m97 structure: 128x128 tile, BK=32, 4 waves (2x2), each wave 4x4 of 16x16 MFMA tiles.
template <int STORE_BF16>
__global__ __launch_bounds__(256) void gemm_bt_128(
    const u16* __restrict__ A, const u16* __restrict__ B,
    const float* __restrict__ bias, void* __restrict__ Cout,
    int M, int N, int K) {
  __shared__ u16 As[128 * 32];
  __shared__ u16 Bs[128 * 32];
  const int tid = threadIdx.x;
  const int lane = tid & 63;
  const int wave = tid >> 6;
  const int wr = (wave >> 1) * 64;
  const int wc = (wave & 1) * 64;
  const int quad = lane >> 4;
  const int l16 = lane & 15;
  const int m0 = blockIdx.y * 128;
  const int n0 = blockIdx.x * 128;

  f32x4 acc[4][4];
  const f32x4 zero = {0.f, 0.f, 0.f, 0.f};
#pragma unroll
  for (int i = 0; i < 4; i++)
#pragma unroll
    for (int j = 0; j < 4; j++) acc[i][j] = zero;

  const int c0 = tid;
  const int c1 = tid + 256;
  const size_t aoff0 = (size_t)(m0 + (c0 >> 2)) * K + (c0 & 3) * 8;
  const size_t aoff1 = (size_t)(m0 + (c1 >> 2)) * K + (c1 & 3) * 8;
  const size_t boff0 = (size_t)(n0 + (c0 >> 2)) * K + (c0 & 3) * 8;
  const size_t boff1 = (size_t)(n0 + (c1 >> 2)) * K + (c1 & 3) * 8;

  for (int k0 = 0; k0 < K; k0 += 32) {
    __syncthreads();
    async16(A + aoff0 + k0, &As[c0 * 8]);
    async16(A + aoff1 + k0, &As[c1 * 8]);
    async16(B + boff0 + k0, &Bs[c0 * 8]);
    async16(B + boff1 + k0, &Bs[c1 * 8]);
    __syncthreads();

    short8 af[4], bf[4];
#pragma unroll
    for (int mi = 0; mi < 4; mi++)
      af[mi] = *(const short8*)&As[(wr + mi * 16 + l16) * 32 + quad * 8];
#pragma unroll
    for (int ni = 0; ni < 4; ni++)
      bf[ni] = *(const short8*)&Bs[(wc + ni * 16 + l16) * 32 + quad * 8];
#pragma unroll
    for (int mi = 0; mi < 4; mi++)
#pragma unroll
      for (int ni = 0; ni < 4; ni++)
        acc[mi][ni] = __builtin_amdgcn_mfma_f32_16x16x32_bf16(af[mi], bf[ni], acc[mi][ni], 0, 0, 0);
  }

#pragma unroll
  for (int mi = 0; mi < 4; mi++) {
#pragma unroll
    for (int ni = 0; ni < 4; ni++) {
      const int col = n0 + wc + ni * 16 + l16;
      const float bv = bias[col];
#pragma unroll
      for (int r = 0; r < 4; r++) {
        const int row = m0 + wr + mi * 16 + quad * 4 + r;
        const float v = acc[mi][ni][r] + bv;
        if (STORE_BF16)
          ((u16*)Cout)[(size_t)row * N + col] = f2bf(v);
        else
          ((float*)Cout)[(size_t)row * N + col] = v;
      }
    }
  }
}

// ---------------- attention core: block = 256 tokens x 1 head ----------------
// grid (N_TOKENS/256, NHEAD). LDS = k+v for this block's (b0, h) only: 8 KB.
// All lanes read the SAME LDS address per instr (pure broadcast, 0 conflicts).
// f32x4 vector math -> v_pk_fma_f32. Boundary blocks (~56/1024) diverge to a
// per-lane global path for lanes with b != b0.
__global__ __launch_bounds__(256, 4) void attn_kernel(
    const u16* __restrict__ q,        // [N_TOKENS, EMBED] bf16
    const float* __restrict__ kproj,  // [B,H,D,L] fp32 (b*8192 + h*1024 + d*16 + l)
    const float* __restrict__ vproj,  // [B,H,L,D] fp32 (b*8192 + h*1024 + l*64 + d)
    const int* __restrict__ bidx,
    u16* __restrict__ ctx) {          // [N_TOKENS, EMBED] bf16
  __shared__ f32x4 sk[256];   // k[d][l]: sk[d*4 + l4], 4 KB
  __shared__ f32x4 sv[256];   // v[l][d]: sv[l*16 + d4], 4 KB
  const int tid = threadIdx.x;
  const int h = blockIdx.y;
  const int n = blockIdx.x * 256 + tid;
  const int b = bidx[n];
  const int b0 = bidx[blockIdx.x * 256];   // block-uniform (scalar load)

  // stage k/v for (b0, h): 256 f32x4 each, 1 per thread, coalesced
  {
    const f32x4* kg = (const f32x4*)(kproj + (size_t)(b0 * NHEAD + h) * 1024);
    const f32x4* vg = (const f32x4*)(vproj + (size_t)(b0 * NHEAD + h) * 1024);
    sk[tid] = kg[tid];
    sv[tid] = vg[tid];
  }

  // q row for (n, h): 64 bf16 = 128 B contiguous per thread
  const u16* qrow = q + (size_t)n * EMBED + h * DHEAD;
  u16x8 qraw[8];
#pragma unroll
  for (int r = 0; r < 8; r++) qraw[r] = *(const u16x8*)(qrow + r * 8);
  __syncthreads();

  float qh[64];
#pragma unroll
  for (int r = 0; r < 8; r++)
#pragma unroll
    for (int j = 0; j < 8; j++) qh[r * 8 + j] = bf2f(qraw[r][j]);

  f32x4 s4[4];
#pragma unroll
  for (int l4 = 0; l4 < 4; l4++) s4[l4] = (f32x4){0.f, 0.f, 0.f, 0.f};

  if (b == b0) {
#pragma unroll
    for (int d = 0; d < 64; d++) {
      const float qd = qh[d];
#pragma unroll
      for (int l4 = 0; l4 < 4; l4++) s4[l4] += qd * sk[d * 4 + l4];
    }
  } else {
    const f32x4* kg = (const f32x4*)(kproj + (size_t)(b * NHEAD + h) * 1024);
#pragma unroll
    for (int d = 0; d < 64; d++) {
      const float qd = qh[d];
#pragma unroll
      for (int l4 = 0; l4 < 4; l4++) s4[l4] += qd * kg[d * 4 + l4];
    }
  }

  float s[16];
#pragma unroll
  for (int l4 = 0; l4 < 4; l4++)
#pragma unroll
    for (int j = 0; j < 4; j++) s[l4 * 4 + j] = s4[l4][j];
  float mx = s[0];
#pragma unroll
  for (int l = 1; l < 16; l++) mx = fmaxf(mx, s[l]);
  float p[16];
  float sum = 0.f;
#pragma unroll
  for (int l = 0; l < 16; l++) {
    p[l] = __expf((s[l] - mx) * 0.125f);   // scale = D^-0.5 folded here
    sum += p[l];
  }
  const float inv = 1.f / sum;

  f32x4 c4[16];
#pragma unroll
  for (int d4 = 0; d4 < 16; d4++) c4[d4] = (f32x4){0.f, 0.f, 0.f, 0.f};

  if (b == b0) {
#pragma unroll
    for (int l = 0; l < 16; l++) {
      const float pl = p[l] * inv;
#pragma unroll
      for (int d4 = 0; d4 < 16; d4++) c4[d4] += pl * sv[l * 16 + d4];
    }
  } else {
    const f32x4* vg = (const f32x4*)(vproj + (size_t)(b * NHEAD + h) * 1024);
#pragma unroll
    for (int l = 0; l < 16; l++) {
      const float pl = p[l] * inv;
#pragma unroll
      for (int d4 = 0; d4 < 16; d4++) c4[d4] += pl * vg[l * 16 + d4];
    }
  }

  u16* orow = ctx + (size_t)n * EMBED + h * DHEAD;
#pragma unroll
  for (int r = 0; r < 8; r++) {
    u16x8 u;
#pragma unroll
    for (int j = 0; j < 8; j++) u[j] = f2bf(c4[(r * 8 + j) >> 2][(r * 8 + j) & 3]);
    *(u16x8*)(orow + r * 8) = u;
  }
}

extern "C" void kernel_launch(void* const* d_in, const int* in_sizes, int n_in,
                              void* d_out, int out_size, void* d_ws, size_t ws_size,
                              hipStream_t stream) {
  const float* query = (const float*)d_in[0];
  const float* keyt = (const float*)d_in[1];
  const float* valt = (const float*)d_in[2];
  const int* bidx = (const int*)d_in[3];
  // d_in[4] = batch_size (scalar, fixed = 8)
  const float* Wq = (const float*)d_in[5];
  const float* bq = (const float*)d_in[6];
  const float* Wk = (const float*)d_in[7];
  const float* bk = (const float*)d_in[8];
  const float* Wv = (const float*)d_in[9];
  const float* bv = (const float*)d_in[10];
  const float* Wo = (const float*)d_in[11];
  const float* bo = (const float*)d_in[12];
  float* out = (float*)d_out;

  // workspace layout (bytes)
  unsigned char* w = (unsigned char*)d_ws;
  u16* qbf = (u16*)(w);                      //  33,554,432: query bf16 [N,E]
  u16* qout = (u16*)(w + 33554432ull);       //  33,554,432: Q bf16 [N,E]
  u16* ctxb = (u16*)(w + 67108864ull);       //  33,554,432: ctx bf16 [N,E]
  u16* wqb = (u16*)(w + 100663296ull);       //     524,288: Wq bf16
  u16* wob = (u16*)(w + 101187584ull);       //     524,288: Wo bf16
  float* kproj = (float*)(w + 101711872ull); //     262,144: [B,H,D,L]
  float* vproj = kproj + 65536;              //     262,144: [B,H,L,D]

  // 1) converts
  cvt_bf16<<<(N_TOKENS * EMBED / 4 + 255) / 256, 256, 0, stream>>>(
      (const float4*)query, (u16x4*)qbf, N_TOKENS * EMBED / 4);
  cvt_bf16<<<(EMBED * EMBED / 4 + 255) / 256, 256, 0, stream>>>(
      (const float4*)Wq, (u16x4*)wqb, EMBED * EMBED / 4);
  cvt_bf16<<<(EMBED * EMBED / 4 + 255) / 256, 256, 0, stream>>>(
      (const float4*)Wo, (u16x4*)wob, EMBED * EMBED / 4);

  // 2) K/V projections
  kvproj_kernel<<<512, 256, 0, stream>>>(keyt, valt, Wk, bk, Wv, bv, kproj, vproj);

  // 3) Q = query @ Wq^T + bq  (bf16 out)
  gemm_bt_128<1><<<dim3(EMBED / 128, N_TOKENS / 128), 256, 0, stream>>>(
      qbf, wqb, bq, qout, N_TOKENS, EMBED, EMBED);

  // 4) attention core (ctx bf16): block = 256 tokens x 1 head, 8 KB LDS
  attn_kernel<<<dim3(N_TOKENS / 256, NHEAD), 256, 0, stream>>>(
      qout, kproj, vproj, bidx, ctxb);

  // 5) out = ctx @ Wo^T + bo (fp32 out)
  gemm_bt_128<0><<<dim3(EMBED / 128, N_TOKENS / 128), 256, 0, stream>>>(
      ctxb, wob, bo, out, N_TOKENS, EMBED, EMBED);
}

// Round 6
// 288.553 us; speedup vs baseline: 1.1825x; 1.1825x over previous
//
#include <hip/hip_runtime.h>

typedef unsigned short u16;
typedef __attribute__((ext_vector_type(8))) short short8;
typedef __attribute__((ext_vector_type(4))) unsigned short u16x4;
typedef __attribute__((ext_vector_type(4))) float f32x4;

#define N_TOKENS 32768
#define EMBED 512
#define NCLS 16
#define NBATCH 8
#define NHEAD 8
#define DHEAD 64

__device__ __forceinline__ u16 f2bf(float f) {
  unsigned u = __float_as_uint(f);
  u += 0x7fffu + ((u >> 16) & 1u);   // RNE
  return (u16)(u >> 16);
}

__device__ __forceinline__ void async16(const u16* g, u16* l) {
  __builtin_amdgcn_global_load_lds(
      (__attribute__((address_space(1))) const unsigned int*)(const void*)g,
      (__attribute__((address_space(3))) unsigned int*)(void*)l,
      16, 0, 0);
}

// ---------------- fp32 -> bf16 converter (4 elems/thread) ----------------
__global__ __launch_bounds__(256) void cvt_bf16(const float4* __restrict__ in,
                                                u16x4* __restrict__ out, int n4) {
  int i = blockIdx.x * blockDim.x + threadIdx.x;
  if (i >= n4) return;
  float4 v = in[i];
  u16x4 o;
  o[0] = f2bf(v.x); o[1] = f2bf(v.y); o[2] = f2bf(v.z); o[3] = f2bf(v.w);
  out[i] = o;
}

// ---------------- K/V projection ----------------
// kproj[b][h][d][l] = sum_e key[l][b][e]*Wk[h*64+d][e] + bk
// vproj[b][h][l][d] = sum_e val[l][b][e]*Wv[h*64+d][e] + bv
__global__ __launch_bounds__(256) void kvproj_kernel(
    const float* __restrict__ key, const float* __restrict__ val,
    const float* __restrict__ Wk, const float* __restrict__ bk,
    const float* __restrict__ Wv, const float* __restrict__ bv,
    float* __restrict__ kproj, float* __restrict__ vproj) {
  int t = blockIdx.x * blockDim.x + threadIdx.x;   // [0, 2*65536)
  const bool isV = t >= 65536;                      // wave-uniform
  int idx = t & 65535;
  int f = idx & 511;
  int bl = idx >> 9;
  int l = bl & 15;
  int b = bl >> 4;
  const float* src = isV ? val : key;
  const float* W = isV ? Wv : Wk;
  const float* bias = isV ? bv : bk;
  const float4* s4 = (const float4*)(src + (size_t)l * (NBATCH * EMBED) + (size_t)b * EMBED);
  const float4* w4 = (const float4*)(W + (size_t)f * EMBED);
  float acc = 0.f;
#pragma unroll 8
  for (int e = 0; e < EMBED / 4; e++) {
    float4 a = s4[e], w = w4[e];
    acc += a.x * w.x + a.y * w.y + a.z * w.z + a.w * w.w;
  }
  acc += bias[f];
  if (!isV) {
    kproj[((size_t)(b * EMBED + f)) * NCLS + l] = acc;           // [b][h][d][l]
  } else {
    int h = f >> 6, d = f & 63;
    vproj[(size_t)b * 8192 + (size_t)h * 1024 + l * 64 + d] = acc;  // [b][h][l][d]
  }
}

// ---------------- Kq[b][hl][e] = sum_d Wq[h*64+d][e] * kproj[b,h,d,l]  (bf16) ----
__global__ __launch_bounds__(256) void build_kq(const float* __restrict__ kproj,
                                                const float* __restrict__ Wq,
                                                u16* __restrict__ Kqb) {
  int t = blockIdx.x * 256 + threadIdx.x;   // 8*128*512
  int e = t & 511;
  int hl = (t >> 9) & 127;
  int b = t >> 16;
  int h = hl >> 4, l = hl & 15;
  const float* kp = kproj + (size_t)b * 8192 + h * 1024 + l;   // stride 16 over d (wave-uniform)
  const float* wq = Wq + (size_t)(h * 64) * 512 + e;           // stride 512 over d (coalesced)
  float acc = 0.f;
#pragma unroll 16
  for (int d = 0; d < 64; d++) acc += kp[d * 16] * wq[d * 512];
  Kqb[t] = f2bf(acc);
}

// ---------------- sb[b][hl] = sum_d bq[h*64+d] * kproj[b,h,d,l] ----------------
__global__ void build_sb(const float* __restrict__ kproj, const float* __restrict__ bq,
                         float* __restrict__ sb) {
  int t = blockIdx.x * 256 + threadIdx.x;   // 1024
  int hl = t & 127, b = t >> 7;
  int h = hl >> 4, l = hl & 15;
  const float* kp = kproj + (size_t)b * 8192 + h * 1024 + l;
  const float* q = bq + h * 64;
  float acc = 0.f;
#pragma unroll
  for (int d = 0; d < 64; d++) acc += q[d] * kp[d * 16];
  sb[t] = acc;
}

// ---------------- WoV[b][f][hl] = sum_d vproj[b,h,l,d] * Wo[f][h*64+d]  (bf16) ----
__global__ __launch_bounds__(256) void build_wov(const float* __restrict__ vproj,
                                                 const float* __restrict__ Wo,
                                                 u16* __restrict__ WoVb) {
  int t = blockIdx.x * 256 + threadIdx.x;   // 8*512*128
  int hl = t & 127;
  int f = (t >> 7) & 511;
  int b = t >> 16;
  int h = hl >> 4, l = hl & 15;
  const float* vp = vproj + (size_t)b * 8192 + h * 1024 + l * 64;  // contiguous d
  const float* wo = Wo + (size_t)f * 512 + h * 64;                 // contiguous d
  float acc = 0.f;
#pragma unroll 16
  for (int d = 0; d < 64; d++) acc += vp[d] * wo[d];
  WoVb[t] = f2bf(acc);
}

// ---------------- scores GEMM + in-block softmax -> P [N,128] bf16 ----------------
// C[128 tok, 128 hl] = qbf[128,512] x Kq[b]^T; tile holds COMPLETE rows so softmax
// over each head's 16 l-cols is a 16-lane shfl_xor reduction. Double-buffered LDS
// with prefetch-after-barrier. bidx sorted -> loop bb over [bFirst, bLast].
__global__ __launch_bounds__(256) void score_gemm(
    const u16* __restrict__ A, const u16* __restrict__ Kqb,
    const float* __restrict__ sb, const int* __restrict__ bidx,
    u16* __restrict__ P) {
  __shared__ u16 As[2][128 * 32];
  __shared__ u16 Bs[2][128 * 32];
  const int tid = threadIdx.x;
  const int lane = tid & 63;
  const int wave = tid >> 6;
  const int wr = (wave >> 1) * 64;
  const int wc = (wave & 1) * 64;
  const int quad = lane >> 4;
  const int l16 = lane & 15;
  const int m0 = blockIdx.x * 128;
  const int bFirst = bidx[m0];
  const int bLast = bidx[m0 + 127];

  const int c0 = tid, c1 = tid + 256;
  const size_t aoff0 = (size_t)(m0 + (c0 >> 2)) * 512 + (c0 & 3) * 8;
  const size_t aoff1 = (size_t)(m0 + (c1 >> 2)) * 512 + (c1 & 3) * 8;
  const size_t boff0 = (size_t)(c0 >> 2) * 512 + (c0 & 3) * 8;
  const size_t boff1 = (size_t)(c1 >> 2) * 512 + (c1 & 3) * 8;

  int rowb[4][4];
#pragma unroll
  for (int mi = 0; mi < 4; mi++)
#pragma unroll
    for (int r = 0; r < 4; r++) rowb[mi][r] = bidx[m0 + wr + mi * 16 + quad * 4 + r];

  for (int bb = bFirst; bb <= bLast; bb++) {
    const u16* B = Kqb + (size_t)bb * 65536;
    f32x4 acc[4][4];
#pragma unroll
    for (int i = 0; i < 4; i++)
#pragma unroll
      for (int j = 0; j < 4; j++) acc[i][j] = (f32x4){0.f, 0.f, 0.f, 0.f};

    // prologue: stage k0=0 into buffer 0
    async16(A + aoff0, &As[0][c0 * 8]);
    async16(A + aoff1, &As[0][c1 * 8]);
    async16(B + boff0, &Bs[0][c0 * 8]);
    async16(B + boff1, &Bs[0][c1 * 8]);

    for (int it = 0; it < 16; it++) {
      __syncthreads();                       // drains vmcnt -> buf[it&1] ready
      const int cur = it & 1, nxt = cur ^ 1;
      if (it < 15) {                         // prefetch next tile; overlaps MFMA below
        const int ko = (it + 1) * 32;
        async16(A + aoff0 + ko, &As[nxt][c0 * 8]);
        async16(A + aoff1 + ko, &As[nxt][c1 * 8]);
        async16(B + boff0 + ko, &Bs[nxt][c0 * 8]);
        async16(B + boff1 + ko, &Bs[nxt][c1 * 8]);
      }
      short8 af[4], bfr[4];
#pragma unroll
      for (int mi = 0; mi < 4; mi++)
        af[mi] = *(const short8*)&As[cur][(wr + mi * 16 + l16) * 32 + quad * 8];
#pragma unroll
      for (int ni = 0; ni < 4; ni++)
        bfr[ni] = *(const short8*)&Bs[cur][(wc + ni * 16 + l16) * 32 + quad * 8];
#pragma unroll
      for (int mi = 0; mi < 4; mi++)
#pragma unroll
        for (int ni = 0; ni < 4; ni++)
          acc[mi][ni] = __builtin_amdgcn_mfma_f32_16x16x32_bf16(af[mi], bfr[ni], acc[mi][ni], 0, 0, 0);
    }

    // epilogue: softmax over each head's 16 l-cols (l16 lanes), predicated store
    float sbv[4];
#pragma unroll
    for (int ni = 0; ni < 4; ni++) sbv[ni] = sb[bb * 128 + wc + ni * 16 + l16];
#pragma unroll
    for (int mi = 0; mi < 4; mi++) {
#pragma unroll
      for (int r = 0; r < 4; r++) {
        const int row = m0 + wr + mi * 16 + quad * 4 + r;
        const bool own = (rowb[mi][r] == bb);
#pragma unroll
        for (int ni = 0; ni < 4; ni++) {
          float v = acc[mi][ni][r] + sbv[ni];
          float mx = v;
          mx = fmaxf(mx, __shfl_xor(mx, 1));
          mx = fmaxf(mx, __shfl_xor(mx, 2));
          mx = fmaxf(mx, __shfl_xor(mx, 4));
          mx = fmaxf(mx, __shfl_xor(mx, 8));
          float ev = __expf((v - mx) * 0.125f);   // scale = D^-0.5
          float s = ev;
          s += __shfl_xor(s, 1);
          s += __shfl_xor(s, 2);
          s += __shfl_xor(s, 4);
          s += __shfl_xor(s, 8);
          if (own) P[(size_t)row * 128 + wc + ni * 16 + l16] = f2bf(ev / s);
        }
      }
    }
  }
}

// ---------------- out GEMM: out[N,512] = P[N,128] x WoV[b]^T(f-major) + bo ----------
// K=128: single-shot LDS staging of both panels (64 KB). Loop bb over tile's range.
// 128x128 u16 tile = 2048 chunks of 8: row = c>>4, chunk = c&15 (16 chunks/row).
__global__ __launch_bounds__(256) void out_gemm(
    const u16* __restrict__ P, const u16* __restrict__ WoVb,
    const float* __restrict__ bo, const int* __restrict__ bidx,
    float* __restrict__ out) {
  __shared__ u16 As[128 * 128];
  __shared__ u16 Bs[128 * 128];
  const int tid = threadIdx.x;
  const int lane = tid & 63;
  const int wave = tid >> 6;
  const int wr = (wave >> 1) * 64;
  const int wc = (wave & 1) * 64;
  const int quad = lane >> 4;
  const int l16 = lane & 15;
  const int m0 = blockIdx.y * 128;
  const int n0 = blockIdx.x * 128;
  const int bFirst = bidx[m0];
  const int bLast = bidx[m0 + 127];

  // stage A (P tile) once: row = c>>4 in [0,128), chunk = c&15
#pragma unroll
  for (int it = 0; it < 8; it++) {
    int c = tid + it * 256;
    async16(P + (size_t)(m0 + (c >> 4)) * 128 + (c & 15) * 8, &As[c * 8]);
  }

  int rowb[4][4];
#pragma unroll
  for (int mi = 0; mi < 4; mi++)
#pragma unroll
    for (int r = 0; r < 4; r++) rowb[mi][r] = bidx[m0 + wr + mi * 16 + quad * 4 + r];
  float bov[4];
#pragma unroll
  for (int ni = 0; ni < 4; ni++) bov[ni] = bo[n0 + wc + ni * 16 + l16];

  for (int bb = bFirst; bb <= bLast; bb++) {
    __syncthreads();   // protect Bs from previous pass readers
    const u16* B = WoVb + (size_t)bb * 65536 + (size_t)n0 * 128;
#pragma unroll
    for (int it = 0; it < 8; it++) {
      int c = tid + it * 256;
      async16(B + (size_t)(c >> 4) * 128 + (c & 15) * 8, &Bs[c * 8]);
    }
    __syncthreads();   // drain: A (first pass) + B ready

    f32x4 acc[4][4];
#pragma unroll
    for (int i = 0; i < 4; i++)
#pragma unroll
      for (int j = 0; j < 4; j++) acc[i][j] = (f32x4){0.f, 0.f, 0.f, 0.f};

#pragma unroll
    for (int kk = 0; kk < 4; kk++) {
      short8 af[4], bfr[4];
#pragma unroll
      for (int mi = 0; mi < 4; mi++)
        af[mi] = *(const short8*)&As[(wr + mi * 16 + l16) * 128 + kk * 32 + quad * 8];
#pragma unroll
      for (int ni = 0; ni < 4; ni++)
        bfr[ni] = *(const short8*)&Bs[(wc + ni * 16 + l16) * 128 + kk * 32 + quad * 8];
#pragma unroll
      for (int mi = 0; mi < 4; mi++)
#pragma unroll
        for (int ni = 0; ni < 4; ni++)
          acc[mi][ni] = __builtin_amdgcn_mfma_f32_16x16x32_bf16(af[mi], bfr[ni], acc[mi][ni], 0, 0, 0);
    }

#pragma unroll
    for (int mi = 0; mi < 4; mi++)
#pragma unroll
      for (int r = 0; r < 4; r++) {
        const int row = m0 + wr + mi * 16 + quad * 4 + r;
        if (rowb[mi][r] == bb) {
#pragma unroll
          for (int ni = 0; ni < 4; ni++)
            out[(size_t)row * 512 + n0 + wc + ni * 16 + l16] = acc[mi][ni][r] + bov[ni];
        }
      }
  }
}

extern "C" void kernel_launch(void* const* d_in, const int* in_sizes, int n_in,
                              void* d_out, int out_size, void* d_ws, size_t ws_size,
                              hipStream_t stream) {
  const float* query = (const float*)d_in[0];
  const float* keyt = (const float*)d_in[1];
  const float* valt = (const float*)d_in[2];
  const int* bidx = (const int*)d_in[3];
  // d_in[4] = batch_size (scalar, fixed = 8)
  const float* Wq = (const float*)d_in[5];
  const float* bq = (const float*)d_in[6];
  const float* Wk = (const float*)d_in[7];
  const float* bk = (const float*)d_in[8];
  const float* Wv = (const float*)d_in[9];
  const float* bv = (const float*)d_in[10];
  const float* Wo = (const float*)d_in[11];
  const float* bo = (const float*)d_in[12];
  float* out = (float*)d_out;

  // workspace layout (bytes)
  unsigned char* w = (unsigned char*)d_ws;
  u16* qbf = (u16*)(w);                       // 33,554,432: query bf16 [N,E]
  u16* P = (u16*)(w + 33554432ull);           //  8,388,608: softmax probs [N,128] bf16
  float* kproj = (float*)(w + 41943040ull);   //    262,144: [B,H,D,L]
  float* vproj = (float*)(w + 42205184ull);   //    262,144: [B,H,L,D]
  u16* Kqb = (u16*)(w + 42467328ull);         //  1,048,576: [B,128,512] bf16
  u16* WoVb = (u16*)(w + 43515904ull);        //  1,048,576: [B,512,128] bf16
  float* sb = (float*)(w + 44564480ull);      //      4,096: [B,128]

  // 1) query -> bf16
  cvt_bf16<<<N_TOKENS * EMBED / 4 / 256, 256, 0, stream>>>(
      (const float4*)query, (u16x4*)qbf, N_TOKENS * EMBED / 4);

  // 2) K/V projections (fp32, tiny)
  kvproj_kernel<<<512, 256, 0, stream>>>(keyt, valt, Wk, bk, Wv, bv, kproj, vproj);

  // 3) fold Wq through k, Wo through v (tiny GEMM-ish precomputes)
  build_kq<<<2048, 256, 0, stream>>>(kproj, Wq, Kqb);
  build_sb<<<4, 256, 0, stream>>>(kproj, bq, sb);
  build_wov<<<2048, 256, 0, stream>>>(vproj, Wo, WoVb);

  // 4) scores = qbf x Kq[b]^T, softmax in-block -> P
  score_gemm<<<N_TOKENS / 128, 256, 0, stream>>>(qbf, Kqb, sb, bidx, P);

  // 5) out = P x WoV[b] + bo
  out_gemm<<<dim3(EMBED / 128, N_TOKENS / 128), 256, 0, stream>>>(P, WoVb, bo, bidx, out);
}